// Round 8
// baseline (428.588 us; speedup 1.0000x reference)
//
#include <hip/hip_runtime.h>
#include <hip/hip_bf16.h>
#include <cstdint>

// MHD PINN loss, fused persistent bf16, wave-specialized pipeline. N=131072, H=256.
// D = W * X^T (m=neuron, n=16pts x 4 streams). Block=512 (8 waves), grid=256, 1 block/CU.
// Waves 0-3 (group A) hold W2 slices (64 neurons each) in regs; waves 4-7 (group B) hold W3.
// Iter i: P1: A: L2(t)->Xmid[i&1]  ||  B: L3(t-1): Xmid[(i-1)&1]->Xout;  barrier;
//         P2: all: L1(t+1)->Xin; wave0: L4+residual(t-1) from Xout;      barrier.
// 2 barriers/iter; L2(t) and L3(t-1) run concurrently on every SIMD (2 waves/SIMD).
// LDS XOR-swizzled (16B chunk ^ row), row stride 512 B.

#define GRIDB 256
#define TPTS 16

typedef __attribute__((ext_vector_type(8))) short v8h;   // 8 x bf16
typedef __attribute__((ext_vector_type(4))) float v4f;

__device__ __forceinline__ ushort f2b(float f) {
    uint32_t u = __float_as_uint(f);
    u = (u + 0x7fffu + ((u >> 16) & 1u)) >> 16;
    return (ushort)u;
}
__device__ __forceinline__ uint32_t pk2(float a, float b) { // v_cvt_pk_bf16_f32
    union { __hip_bfloat162 h2; uint32_t u; } cv;
    cv.h2 = __float22bfloat162_rn(make_float2(a, b));
    return cv.u;
}
__device__ __forceinline__ float fast_tanh(float x) {
    float e = __expf(2.0f * x);
    return 1.0f - 2.0f * __builtin_amdgcn_rcpf(e + 1.0f);
}
__device__ __forceinline__ int swz(int row, int bytecol) {
    return (row << 9) + ((((bytecol >> 4) ^ (row & 31)) << 4) | (bytecol & 15));
}

// prep: W2,W3 (256x256 [k][n]) -> bf16 transposed Wt[n][k]; W4 (256x6) -> Wt4[16][256]
__global__ void prep_weights(const float* __restrict__ W2, const float* __restrict__ W3,
                             const float* __restrict__ W4,
                             ushort* __restrict__ Wt2, ushort* __restrict__ Wt3,
                             ushort* __restrict__ Wt4) {
    int idx = blockIdx.x * 256 + threadIdx.x;
    if (idx < 65536) {
        int k = idx >> 8, n = idx & 255;
        Wt2[n * 256 + k] = f2b(W2[k * 256 + n]);
        Wt3[n * 256 + k] = f2b(W3[k * 256 + n]);
    }
    if (idx < 4096) {
        int n = idx >> 8, k = idx & 255;
        Wt4[n * 256 + k] = (n < 6) ? f2b(W4[k * 6 + n]) : (ushort)0;
    }
}

__global__ __launch_bounds__(512, 2)
void mhd_fused(const float* __restrict__ coords,
               const float* __restrict__ W1, const float* __restrict__ b1,
               const float* __restrict__ b2, const float* __restrict__ b3,
               const float* __restrict__ b4,
               const float* __restrict__ wts,
               const ushort* __restrict__ Wt2, const ushort* __restrict__ Wt3,
               const ushort* __restrict__ Wt4,
               float* __restrict__ out, int npts, float inv_n) {
    __shared__ __align__(16) uint8_t Xin[64 * 512];
    __shared__ __align__(16) uint8_t XmidB[2][64 * 512];
    __shared__ __align__(16) uint8_t Xout[64 * 512];
    __shared__ __align__(16) uint8_t W4s[16 * 512];
    __shared__ float Ys[4][8][17];

    const int tid  = threadIdx.x;
    const int lane = tid & 63;
    const int wv   = tid >> 6;      // 0..7
    const int grp  = wv >> 2;       // 0 = A (W2/L2), 1 = B (W3/L3)
    const int wvg  = wv & 3;        // wave index within group
    const int q    = lane >> 4;
    const int l15  = lane & 15;

    // ---- stage W4 (16x256 bf16) into swizzled LDS ----------------------------
    for (int idx = tid; idx < 16 * 128; idx += 512) {     // dword units
        int n = idx >> 7, kdw = idx & 127;
        *(uint32_t*)(&W4s[(n << 9) + ((((kdw >> 2) ^ n) << 4) | ((kdw & 3) << 2))]) =
            ((const uint32_t*)Wt4)[idx];
    }

    // ---- this wave's weight matrix (64 neurons) -> registers (AGPR) ----------
    const ushort* Wsrc = grp ? Wt3 : Wt2;
    const float*  bias = grp ? b3  : b2;
    v8h wf[4][8];
    #pragma unroll
    for (int mt = 0; mt < 4; mt++) {
        const int nrow = (wvg * 64 + mt * 16 + l15) * 256 + q * 8;
        #pragma unroll
        for (int kk = 0; kk < 8; kk++)
            wf[mt][kk] = *(const v8h*)(&Wsrc[nrow + kk * 32]);
    }

    // ---- L1 constants: 2 cols/thread, 4 pts ----------------------------------
    const int j0 = (tid & 127) * 2, pg4 = (tid >> 7) * 4;
    const float w0a = W1[j0],       w0b = W1[j0 + 1];
    const float w1a = W1[256 + j0], w1b = W1[257 + j0];
    const float w2a = W1[512 + j0], w2b = W1[513 + j0];
    const float b1a = b1[j0],       b1b = b1[j0 + 1];

    const float b40 = b4[0], b41 = b4[1], b42 = b4[2], b43 = b4[3], b44 = b4[4], b45 = b4[5];
    const float wt0 = wts[0], wt1 = wts[1], wt2_ = wts[2], wt3_ = wts[3],
                wt4_ = wts[4], wt5 = wts[5], wt6 = wts[6];

    auto do_l1 = [&](int tile) {
        const int base = tile * TPTS;
        #pragma unroll
        for (int pp = 0; pp < 4; pp++) {
            const int p = pg4 + pp;
            int gp = base + p; if (gp >= npts) gp = npts - 1;
            float x = coords[gp * 3], y = coords[gp * 3 + 1], t = coords[gp * 3 + 2];
            float ha = fast_tanh(fmaf(x, w0a, fmaf(y, w1a, fmaf(t, w2a, b1a))));
            float hb = fast_tanh(fmaf(x, w0b, fmaf(y, w1b, fmaf(t, w2b, b1b))));
            float da = 1.0f - ha * ha, db = 1.0f - hb * hb;
            const int bc = j0 * 2;
            *(uint32_t*)(&Xin[swz(p, bc)])      = pk2(ha, hb);
            *(uint32_t*)(&Xin[swz(16 + p, bc)]) = pk2(da * w0a, db * w0b);
            *(uint32_t*)(&Xin[swz(32 + p, bc)]) = pk2(da * w1a, db * w1b);
            *(uint32_t*)(&Xin[swz(48 + p, bc)]) = pk2(da * w2a, db * w2b);
        }
    };

    // one dense layer slice: this wave's 64 neurons, src -> dst (both swizzled)
    auto dense = [&](const uint8_t* src, uint8_t* dst) {
        v4f acc[4][4];
        #pragma unroll
        for (int a = 0; a < 4; a++)
            #pragma unroll
            for (int b = 0; b < 4; b++) {
                v4f z = {0.0f, 0.0f, 0.0f, 0.0f};
                acc[a][b] = z;
            }
        #pragma unroll
        for (int kk = 0; kk < 8; kk++) {
            v8h B[4];
            #pragma unroll
            for (int nt = 0; nt < 4; nt++) {
                const int row = nt * 16 + l15;
                B[nt] = *(const v8h*)(&src[(row << 9) + ((((kk * 4 + q) ^ (row & 31)) << 4))]);
            }
            #pragma unroll
            for (int mt = 0; mt < 4; mt++)
                #pragma unroll
                for (int nt = 0; nt < 4; nt++)
                    acc[mt][nt] = __builtin_amdgcn_mfma_f32_16x16x32_bf16(wf[mt][kk], B[nt], acc[mt][nt], 0, 0, 0);
        }
        // D row (neuron) = mt*16+q*4+r, D col = nt*16+l15 (stream nt, point l15)
        #pragma unroll
        for (int mt = 0; mt < 4; mt++) {
            v4f bb = *(const v4f*)(&bias[wvg * 64 + mt * 16 + q * 4]);
            float h0 = fast_tanh(acc[mt][0][0] + bb[0]);
            float h1 = fast_tanh(acc[mt][0][1] + bb[1]);
            float h2 = fast_tanh(acc[mt][0][2] + bb[2]);
            float h3 = fast_tanh(acc[mt][0][3] + bb[3]);
            float d0 = 1.0f - h0 * h0, d1 = 1.0f - h1 * h1;
            float d2 = 1.0f - h2 * h2, d3 = 1.0f - h3 * h3;
            const int bc = wvg * 128 + mt * 32 + q * 8;
            uint2 w;
            w.x = pk2(h0, h1); w.y = pk2(h2, h3);
            *(uint2*)(&dst[swz(l15, bc)]) = w;
            #pragma unroll
            for (int s = 1; s < 4; s++) {
                w.x = pk2(d0 * acc[mt][s][0], d1 * acc[mt][s][1]);
                w.y = pk2(d2 * acc[mt][s][2], d3 * acc[mt][s][3]);
                *(uint2*)(&dst[swz(s * 16 + l15, bc)]) = w;
            }
        }
    };

    // L4 (whole tile, one wave) + residual for 16 points on lanes 0..15
    auto l4res = [&](int tile) -> float {
        v4f a4[4];
        #pragma unroll
        for (int nt = 0; nt < 4; nt++) { v4f z = {0.0f, 0.0f, 0.0f, 0.0f}; a4[nt] = z; }
        #pragma unroll
        for (int kk = 0; kk < 8; kk++) {
            v8h A = *(const v8h*)(&W4s[(l15 << 9) + (((kk * 4 + q) ^ l15) << 4)]);
            #pragma unroll
            for (int nt = 0; nt < 4; nt++) {
                const int row = nt * 16 + l15;
                v8h B = *(const v8h*)(&Xout[(row << 9) + ((((kk * 4 + q) ^ (row & 31)) << 4))]);
                a4[nt] = __builtin_amdgcn_mfma_f32_16x16x32_bf16(A, B, a4[nt], 0, 0, 0);
            }
        }
        if (q < 2) {
            #pragma unroll
            for (int nt = 0; nt < 4; nt++)
                #pragma unroll
                for (int r = 0; r < 4; r++)
                    Ys[nt][q * 4 + r][l15] = a4[nt][r];
        }
        float v = 0.0f;
        if (lane < 16 && (tile * TPTS + lane) < npts) {
            float Yv[4][6];
            #pragma unroll
            for (int s = 0; s < 4; s++)
                #pragma unroll
                for (int k = 0; k < 6; k++)
                    Yv[s][k] = Ys[s][k][lane];
            const float* Yh = Yv[0];
            const float* JX = Yv[1];
            const float* JY = Yv[2];
            const float* JT = Yv[3];
            const float g1 = 1.5f;
            float rho = Yh[0] + b40, vx = Yh[1] + b41, vy = Yh[2] + b42;
            float Bx  = Yh[3] + b43, By = Yh[4] + b44, P  = Yh[5] + b45;
            float v2 = vx * vx + vy * vy;
            float dt_rho = JT[0];
            float dt_rhovx = dt_rho * vx + rho * JT[1];
            float dt_rhovy = dt_rho * vy + rho * JT[2];
            auto dE = [&](const float* J) {
                return J[5] * g1 + 0.5f * J[0] * v2 + rho * (vx * J[1] + vy * J[2]) + Bx * J[3] + By * J[4];
            };
            float dE_dx = dE(JX), dE_dy = dE(JY), dE_dt = dE(JT);
            float div_v = JX[1] + JY[2];
            float div_B = JX[3] + JY[4];
            float continuity = dt_rho + rho * div_v;
            float dPm_dx = JX[5] + Bx * JX[3] + By * JX[4];
            float dPm_dy = JY[5] + Bx * JY[3] + By * JY[4];
            float momentum_x = dt_rhovx + dPm_dx - (Bx * JX[3] + By * JY[3]);
            float momentum_y = dt_rhovy + dPm_dy - (Bx * JX[4] + By * JY[4]);
            auto dG = [&](const float* J) {
                return J[1] * By + vx * J[4] - J[2] * Bx - vy * J[3];
            };
            float induction_x = JT[3] + dG(JY);
            float induction_y = JT[4] - dG(JX);
            float E = P * g1 + 0.5f * rho * v2 + 0.5f * (Bx * Bx + By * By);
            float S = E + P + 0.5f * (Bx * Bx + By * By);
            float dS_dx = dE_dx + JX[5] + Bx * JX[3] + By * JX[4];
            float dS_dy = dE_dy + JY[5] + Bx * JY[3] + By * JY[4];
            float D = Bx * vx + By * vy;
            auto dD = [&](const float* J) {
                return J[3] * vx + Bx * J[1] + J[4] * vy + By * J[2];
            };
            float dFx_dx = dS_dx * vx + S * JX[1] - dD(JX) * Bx - D * JX[3];
            float dFy_dy = dS_dy * vy + S * JY[2] - dD(JY) * By - D * JY[4];
            float energy = dE_dt + dFx_dx + dFy_dy;
            v = wt0 * continuity * continuity
              + wt1 * momentum_x * momentum_x
              + wt2_ * momentum_y * momentum_y
              + wt3_ * induction_x * induction_x
              + wt4_ * induction_y * induction_y
              + wt5 * energy * energy
              + wt6 * div_B * div_B;
        }
        return v;
    };

    const int ntiles = (npts + TPTS - 1) / TPTS;
    const int myblk  = blockIdx.x;
    const int nit    = (myblk < ntiles) ? ((ntiles - 1 - myblk) / GRIDB + 1) : 0;
    float vsum = 0.0f;

    if (nit > 0) do_l1(myblk);      // prologue: L1 for tile 0
    __syncthreads();

    for (int i = 0; i <= nit; i++) {
        // ---- P1: A: L2(tile i) -> Xmid[i&1]  ||  B: L3(tile i-1) -> Xout ------
        if (grp == 0) {
            if (i < nit) dense(Xin, XmidB[i & 1]);
        } else {
            if (i >= 1) dense(XmidB[(i - 1) & 1], Xout);
        }
        __syncthreads();
        // ---- P2: all: L1(tile i+1) -> Xin; wave0: L4+residual(tile i-1) -------
        if (i + 1 < nit) do_l1(myblk + (i + 1) * GRIDB);
        if (wv == 0 && i >= 1) vsum += l4res(myblk + (i - 1) * GRIDB);
        __syncthreads();
    }

    if (wv == 0) {
        #pragma unroll
        for (int off = 8; off >= 1; off >>= 1)
            vsum += __shfl_down(vsum, off, 64);
        if (lane == 0) atomicAdd(out, vsum * inv_n);
    }
}

extern "C" void kernel_launch(void* const* d_in, const int* in_sizes, int n_in,
                              void* d_out, int out_size, void* d_ws, size_t ws_size,
                              hipStream_t stream) {
    const float* coords = (const float*)d_in[0];
    const float* W1 = (const float*)d_in[1];
    const float* b1 = (const float*)d_in[2];
    const float* W2 = (const float*)d_in[3];
    const float* b2 = (const float*)d_in[4];
    const float* W3 = (const float*)d_in[5];
    const float* b3 = (const float*)d_in[6];
    const float* W4 = (const float*)d_in[7];
    const float* b4 = (const float*)d_in[8];
    const float* wts = (const float*)d_in[9];
    const int npts = in_sizes[0] / 3;

    ushort* Wt2 = (ushort*)d_ws;
    ushort* Wt3 = Wt2 + 65536;
    ushort* Wt4 = Wt3 + 65536;

    (void)hipMemsetAsync(d_out, 0, sizeof(float), stream);
    prep_weights<<<256, 256, 0, stream>>>(W2, W3, W4, Wt2, Wt3, Wt4);
    mhd_fused<<<GRIDB, 512, 0, stream>>>(coords, W1, b1, b2, b3, b4, wts,
                                         Wt2, Wt3, Wt4, (float*)d_out, npts, 1.0f / npts);
}